// Round 10
// baseline (324.928 us; speedup 1.0000x reference)
//
#include <hip/hip_runtime.h>
#include <hip/hip_fp16.h>

// Integration_block: scaling-and-squaring SVF integration.
// flow = SVF * 2^-7; 7x: flow = flow + trilerp(flow, p + flow), zeros padding.
// Shape (1, 3, 160, 192, 224) fp32 planar in/out.
//
// Intermediates: fp16 PADDED 8 B/voxel (x,y,z,pad). Each thread handles TWO
// voxels (d, d+1): 2 own-loads then 8 gather windows issued back-to-back
// (doubles per-wave outstanding requests vs R9 -- the latency-exposure fix).
// All accesses naturally aligned; no sub-dword ops. 256-thread blocks.

#define D_ 160
#define H_ 192
#define W_ 224
static constexpr int NV = D_ * H_ * W_;   // 6,881,280
static constexpr int HW = H_ * W_;
static constexpr float S_ = 0.0078125f;   // 2^-7
typedef unsigned int u32;

struct __attribute__((packed, aligned(8))) U4 { u32 a, b, c, d; };
struct __attribute__((packed, aligned(8))) U2 { u32 a, b; };

__device__ __forceinline__ float2 h2f(u32 h) {
    __half2 x = *(__half2*)&h;
    return __half22float2(x);
}
__device__ __forceinline__ u32 pk(float a, float b) {
    __half2 h = __floats2half2_rn(a, b);
    return *(u32*)&h;
}
__device__ __forceinline__ float h1f(u32 bits16) {
    __half_raw r; r.x = (unsigned short)bits16;
    return __half2float(__half(r));
}

// planar fp32 SVF -> padded fp16 interleaved (2 u32/voxel), scale folded.
__global__ __launch_bounds__(256) void scale_k(const float* __restrict__ svf,
                                               u32* __restrict__ out) {
    const int i = blockIdx.x * 256 + threadIdx.x;   // NV/4 ids
    float4 a = ((const float4*)svf)[i];
    float4 b = ((const float4*)(svf + NV))[i];
    float4 c = ((const float4*)(svf + 2 * NV))[i];
    u32* o = out + 8 * (size_t)i;
    o[0] = pk(a.x * S_, b.x * S_);  o[1] = pk(c.x * S_, 0.f);
    o[2] = pk(a.y * S_, b.y * S_);  o[3] = pk(c.y * S_, 0.f);
    o[4] = pk(a.z * S_, b.z * S_);  o[5] = pk(c.z * S_, 0.f);
    o[6] = pk(a.w * S_, b.w * S_);  o[7] = pk(c.w * S_, 0.f);
}

// trilerp from 4 aligned 16B windows (corner layout: (xy, z_) (xy, z_))
__device__ __forceinline__ void lerp_windows(const U4& u0, const U4& u1,
                                             const U4& u2, const U4& u3,
                                             float fd, float fh, float fw,
                                             float& a0, float& a1, float& a2) {
    const float ww1 = fw, ww0 = 1.f - fw;
    const float wh1 = fh, wh0 = 1.f - fh;
    const float wd1 = fd, wd0 = 1.f - fd;
    const float c00 = wd0 * wh0, c01 = wd0 * wh1;
    const float c10 = wd1 * wh0, c11 = wd1 * wh1;
    {
        const float2 q0 = h2f(u0.a), q1 = h2f(u0.c);
        const float z0 = h1f(u0.b & 0xffffu), z1 = h1f(u0.d & 0xffffu);
        a0 = c00 * (ww0 * q0.x + ww1 * q1.x);
        a1 = c00 * (ww0 * q0.y + ww1 * q1.y);
        a2 = c00 * (ww0 * z0 + ww1 * z1);
    }
    {
        const float2 q0 = h2f(u1.a), q1 = h2f(u1.c);
        const float z0 = h1f(u1.b & 0xffffu), z1 = h1f(u1.d & 0xffffu);
        a0 += c01 * (ww0 * q0.x + ww1 * q1.x);
        a1 += c01 * (ww0 * q0.y + ww1 * q1.y);
        a2 += c01 * (ww0 * z0 + ww1 * z1);
    }
    {
        const float2 q0 = h2f(u2.a), q1 = h2f(u2.c);
        const float z0 = h1f(u2.b & 0xffffu), z1 = h1f(u2.d & 0xffffu);
        a0 += c10 * (ww0 * q0.x + ww1 * q1.x);
        a1 += c10 * (ww0 * q0.y + ww1 * q1.y);
        a2 += c10 * (ww0 * z0 + ww1 * z1);
    }
    {
        const float2 q0 = h2f(u3.a), q1 = h2f(u3.c);
        const float z0 = h1f(u3.b & 0xffffu), z1 = h1f(u3.d & 0xffffu);
        a0 += c11 * (ww0 * q0.x + ww1 * q1.x);
        a1 += c11 * (ww0 * q0.y + ww1 * q1.y);
        a2 += c11 * (ww0 * z0 + ww1 * z1);
    }
}

// general path: per-corner bounds-checked gather (zeros padding)
__device__ __forceinline__ void lerp_general(const u32* __restrict__ in,
                                             int d0, int h0, int w0,
                                             float fd, float fh, float fw,
                                             float& a0, float& a1, float& a2) {
    a0 = a1 = a2 = 0.f;
    const __half* hp = (const __half*)in;
#pragma unroll
    for (int dz = 0; dz < 2; ++dz) {
        const int cd = d0 + dz;
        if ((unsigned)cd >= (unsigned)D_) continue;
        const float wz = dz ? fd : (1.f - fd);
#pragma unroll
        for (int dy = 0; dy < 2; ++dy) {
            const int ch = h0 + dy;
            if ((unsigned)ch >= (unsigned)H_) continue;
            const float wzy = wz * (dy ? fh : (1.f - fh));
            const int rowbase = (cd * H_ + ch) * W_;
#pragma unroll
            for (int dx = 0; dx < 2; ++dx) {
                const int cw = w0 + dx;
                if ((unsigned)cw >= (unsigned)W_) continue;
                const float wt = wzy * (dx ? fw : (1.f - fw));
                const int j = 4 * (rowbase + cw);
                a0 += wt * __half2float(hp[j]);
                a1 += wt * __half2float(hp[j + 1]);
                a2 += wt * __half2float(hp[j + 2]);
            }
        }
    }
}

template <int PLANAR_OUT>
__global__ __launch_bounds__(256) void compose_k(const u32* __restrict__ in,
                                                 void* __restrict__ out_) {
    const int w = blockIdx.x * 32 + threadIdx.x;        // 224/32 = 7
    const int h = blockIdx.y * 4 + threadIdx.y;         // 192/4  = 48
    const int d = (blockIdx.z * 2 + threadIdx.z) * 2;   // 160/4  = 40 (2 vox/thread)
    const int idx0 = (d * H_ + h) * W_ + w;
    const int idx1 = idx0 + HW;

    // both own-loads in flight together
    const U2 uoA = *(const U2*)(in + 2 * (size_t)idx0);
    const U2 uoB = *(const U2*)(in + 2 * (size_t)idx1);

    const float2 fA01 = h2f(uoA.a);
    const float fA0 = fA01.x, fA1 = fA01.y, fA2 = h1f(uoA.b & 0xffffu);
    const float2 fB01 = h2f(uoB.a);
    const float fB0 = fB01.x, fB1 = fB01.y, fB2 = h1f(uoB.b & 0xffffu);

    const float pdA = (float)d + fA0,       phA = (float)h + fA1, pwA = (float)w + fA2;
    const float pdB = (float)(d + 1) + fB0, phB = (float)h + fB1, pwB = (float)w + fB2;

    const float dAf = floorf(pdA), hAf = floorf(phA), wAf = floorf(pwA);
    const float dBf = floorf(pdB), hBf = floorf(phB), wBf = floorf(pwB);
    const int d0A = (int)dAf, h0A = (int)hAf, w0A = (int)wAf;
    const int d0B = (int)dBf, h0B = (int)hBf, w0B = (int)wBf;
    const float fdA = pdA - dAf, fhA = phA - hAf, fwA = pwA - wAf;
    const float fdB = pdB - dBf, fhB = phB - hBf, fwB = pwB - wBf;

    const bool intA = ((unsigned)d0A <= (unsigned)(D_ - 2)) &
                      ((unsigned)h0A <= (unsigned)(H_ - 2)) &
                      ((unsigned)w0A <= (unsigned)(W_ - 2));
    const bool intB = ((unsigned)d0B <= (unsigned)(D_ - 2)) &
                      ((unsigned)h0B <= (unsigned)(H_ - 2)) &
                      ((unsigned)w0B <= (unsigned)(W_ - 2));

    float aA0, aA1, aA2, aB0, aB1, aB2;

    if (intA & intB) {
        const int jA = (d0A * H_ + h0A) * W_ + w0A;
        const int jB = (d0B * H_ + h0B) * W_ + w0B;
        // 8 gather windows issued back-to-back (one vmcnt round)
        const U4 uA0 = *(const U4*)(in + 2 * (size_t)jA);
        const U4 uA1 = *(const U4*)(in + 2 * (size_t)(jA + W_));
        const U4 uA2 = *(const U4*)(in + 2 * (size_t)(jA + HW));
        const U4 uA3 = *(const U4*)(in + 2 * (size_t)(jA + HW + W_));
        const U4 uB0 = *(const U4*)(in + 2 * (size_t)jB);
        const U4 uB1 = *(const U4*)(in + 2 * (size_t)(jB + W_));
        const U4 uB2 = *(const U4*)(in + 2 * (size_t)(jB + HW));
        const U4 uB3 = *(const U4*)(in + 2 * (size_t)(jB + HW + W_));

        lerp_windows(uA0, uA1, uA2, uA3, fdA, fhA, fwA, aA0, aA1, aA2);
        lerp_windows(uB0, uB1, uB2, uB3, fdB, fhB, fwB, aB0, aB1, aB2);
    } else {
        lerp_general(in, d0A, h0A, w0A, fdA, fhA, fwA, aA0, aA1, aA2);
        lerp_general(in, d0B, h0B, w0B, fdB, fhB, fwB, aB0, aB1, aB2);
    }

    const float oA0 = fA0 + aA0, oA1 = fA1 + aA1, oA2 = fA2 + aA2;
    const float oB0 = fB0 + aB0, oB1 = fB1 + aB1, oB2 = fB2 + aB2;

    if (PLANAR_OUT) {
        float* out = (float*)out_;
        out[idx0] = oA0; out[NV + idx0] = oA1; out[2 * NV + idx0] = oA2;
        out[idx1] = oB0; out[NV + idx1] = oB1; out[2 * NV + idx1] = oB2;
    } else {
        U2 oA; oA.a = pk(oA0, oA1); oA.b = pk(oA2, 0.f);
        U2 oB; oB.a = pk(oB0, oB1); oB.b = pk(oB2, 0.f);
        *(U2*)((u32*)out_ + 2 * (size_t)idx0) = oA;
        *(U2*)((u32*)out_ + 2 * (size_t)idx1) = oB;
    }
}

extern "C" void kernel_launch(void* const* d_in, const int* in_sizes, int n_in,
                              void* d_out, int out_size, void* d_ws, size_t ws_size,
                              hipStream_t stream) {
    const float* svf = (const float*)d_in[0];
    float* outp = (float*)d_out;           // final planar fp32 output
    u32* X0 = (u32*)d_ws;                  // padded fp16 scratch A (55 MB)
    u32* X1 = (u32*)d_out;                 // padded fp16 scratch B in d_out

    scale_k<<<NV / 4 / 256, 256, 0, stream>>>(svf, X0);

    dim3 blk(32, 4, 2);
    dim3 grd(W_ / 32, H_ / 4, D_ / 4);     // (7, 48, 40)

    compose_k<0><<<grd, blk, 0, stream>>>(X0, X1);
    compose_k<0><<<grd, blk, 0, stream>>>(X1, X0);
    compose_k<0><<<grd, blk, 0, stream>>>(X0, X1);
    compose_k<0><<<grd, blk, 0, stream>>>(X1, X0);
    compose_k<0><<<grd, blk, 0, stream>>>(X0, X1);
    compose_k<0><<<grd, blk, 0, stream>>>(X1, X0);
    compose_k<1><<<grd, blk, 0, stream>>>(X0, outp);
}

// Round 12
// 280.850 us; speedup vs baseline: 1.1569x; 1.1569x over previous
//
#include <hip/hip_runtime.h>
#include <hip/hip_fp16.h>

// Integration_block: scaling-and-squaring SVF integration.
// flow = SVF * 2^-7; 7x: flow = flow + trilerp(flow, p + flow), zeros padding.
// Shape (1, 3, 160, 192, 224) fp32 planar in/out.
//
// R12 = R7 (best, 286us: fp16 tight 6B/voxel interleaved intermediates,
// 1 voxel/thread, covering 16B gather windows) + XCD-aware block swizzle:
// consecutive hardware blockIdx round-robin across the 8 XCDs, so we remap
// bid -> work so each XCD owns a contiguous 20-plane d-slab walked h-major.
// Instantaneous per-XCD src working set ~2MB < 4MB XCD-L2 -> gather rows
// shared by h/d-neighbor blocks become L2 hits instead of LLC refetches.

#define D_ 160
#define H_ 192
#define W_ 224
static constexpr int NV = D_ * H_ * W_;   // 6,881,280
static constexpr float S_ = 0.0078125f;   // 2^-7
typedef unsigned int u32;

// blocks: (w 7) x (h 48) x (d 80) = 26880; per XCD 3360 = 10 d-blocks x 336
static constexpr int NWG   = 26880;
static constexpr int PERX  = NWG / 8;     // 3360
static constexpr int PERD2 = 7 * 48;      // 336 blocks per d-block

struct __attribute__((packed, aligned(4))) U4 { u32 a, b, c, d; };
struct __attribute__((packed, aligned(4))) U2 { u32 a, b; };

__device__ __forceinline__ float2 h2f(u32 h) {
    __half2 x = *(__half2*)&h;
    return __half22float2(x);
}
__device__ __forceinline__ u32 pk(float a, float b) {
    __half2 h = __floats2half2_rn(a, b);
    return *(u32*)&h;
}
__device__ __forceinline__ float h1f(u32 bits16) {
    __half_raw r; r.x = (unsigned short)bits16;
    return __half2float(__half(r));
}

// planar fp32 SVF -> tight fp16 interleaved, scale folded. 4 voxels/thread.
__global__ __launch_bounds__(256) void scale_k(const float* __restrict__ svf,
                                               u32* __restrict__ out) {
    const int i = blockIdx.x * 256 + threadIdx.x;   // NV/4 ids
    float4 a = ((const float4*)svf)[i];
    float4 b = ((const float4*)(svf + NV))[i];
    float4 c = ((const float4*)(svf + 2 * NV))[i];
    u32* o = out + 6 * (size_t)i;
    o[0] = pk(a.x * S_, b.x * S_);
    o[1] = pk(c.x * S_, a.y * S_);
    o[2] = pk(b.y * S_, c.y * S_);
    o[3] = pk(a.z * S_, b.z * S_);
    o[4] = pk(c.z * S_, a.w * S_);
    o[5] = pk(b.w * S_, c.w * S_);
}

// Extract two voxels' xyz (6 halves) from a 16B window with half-parity s.
__device__ __forceinline__ void extract6(const U4& u, int s, float2& p0,
                                         float2& p1, float2& p2) {
    const u32 v0 = s ? ((u.a >> 16) | (u.b << 16)) : u.a;
    const u32 v1 = s ? ((u.b >> 16) | (u.c << 16)) : u.b;
    const u32 v2 = s ? ((u.c >> 16) | (u.d << 16)) : u.c;
    p0 = h2f(v0);   // x0 y0
    p1 = h2f(v1);   // z0 x1
    p2 = h2f(v2);   // y1 z1
}

template <int PLANAR_OUT>
__global__ __launch_bounds__(256) void compose_k(const u32* __restrict__ in,
                                                 void* __restrict__ out_) {
    // XCD-aware swizzle: consecutive bids round-robin XCDs; give each XCD a
    // contiguous chunk of d-major work. Bijective since NWG % 8 == 0.
    const int bid = blockIdx.x;
    const int wk  = (bid & 7) * PERX + (bid >> 3);
    const int db2 = wk / PERD2;               // d-block index [0,80)
    const int rem = wk - db2 * PERD2;
    const int hb  = rem / 7;                  // h-block [0,48)
    const int wb  = rem - hb * 7;             // w-block [0,7)

    const int w = wb * 32 + threadIdx.x;
    const int h = hb * 4 + threadIdx.y;
    const int d = db2 * 2 + threadIdx.z;
    const int idx = (d * H_ + h) * W_ + w;

    // own flow: halves [3idx, 3idx+2]
    const int Ho = 3 * idx;
    const U2 uo = *(const U2*)(in + (Ho >> 1));
    const int so = Ho & 1;
    const u32 vo = so ? ((uo.a >> 16) | (uo.b << 16)) : uo.a;
    const float2 xy = h2f(vo);
    const float f0 = xy.x;
    const float f1 = xy.y;
    const float f2 = h1f(so ? (uo.b >> 16) : (uo.b & 0xffffu));

    const float pd = (float)d + f0;
    const float ph = (float)h + f1;
    const float pw = (float)w + f2;
    const float d0f = floorf(pd), h0f = floorf(ph), w0f = floorf(pw);
    const int d0 = (int)d0f, h0 = (int)h0f, w0 = (int)w0f;
    const float fd = pd - d0f, fh = ph - h0f, fw = pw - w0f;

    float acc0, acc1, acc2;

    const bool interior = ((unsigned)d0 <= (unsigned)(D_ - 2)) &
                          ((unsigned)h0 <= (unsigned)(H_ - 2)) &
                          ((unsigned)w0 <= (unsigned)(W_ - 2));

    if (interior) {
        const int j00 = (d0 * H_ + h0) * W_ + w0;
        const int j01 = j00 + W_;
        const int j10 = j00 + H_ * W_;
        const int j11 = j10 + W_;
        const int H00 = 3 * j00, H01 = 3 * j01, H10 = 3 * j10, H11 = 3 * j11;
        // issue all 4 covering loads up front
        const U4 u0 = *(const U4*)(in + (H00 >> 1));
        const U4 u1 = *(const U4*)(in + (H01 >> 1));
        const U4 u2 = *(const U4*)(in + (H10 >> 1));
        const U4 u3 = *(const U4*)(in + (H11 >> 1));

        const float ww1 = fw, ww0 = 1.f - fw;
        const float wh1 = fh, wh0 = 1.f - fh;
        const float wd1 = fd, wd0 = 1.f - fd;
        const float c00 = wd0 * wh0, c01 = wd0 * wh1;
        const float c10 = wd1 * wh0, c11 = wd1 * wh1;

        acc0 = 0.f; acc1 = 0.f; acc2 = 0.f;

        {
            float2 p0, p1, p2;
            extract6(u0, H00 & 1, p0, p1, p2);
            acc0 += c00 * (ww0 * p0.x + ww1 * p1.y);
            acc1 += c00 * (ww0 * p0.y + ww1 * p2.x);
            acc2 += c00 * (ww0 * p1.x + ww1 * p2.y);
        }
        {
            float2 p0, p1, p2;
            extract6(u1, H01 & 1, p0, p1, p2);
            acc0 += c01 * (ww0 * p0.x + ww1 * p1.y);
            acc1 += c01 * (ww0 * p0.y + ww1 * p2.x);
            acc2 += c01 * (ww0 * p1.x + ww1 * p2.y);
        }
        {
            float2 p0, p1, p2;
            extract6(u2, H10 & 1, p0, p1, p2);
            acc0 += c10 * (ww0 * p0.x + ww1 * p1.y);
            acc1 += c10 * (ww0 * p0.y + ww1 * p2.x);
            acc2 += c10 * (ww0 * p1.x + ww1 * p2.y);
        }
        {
            float2 p0, p1, p2;
            extract6(u3, H11 & 1, p0, p1, p2);
            acc0 += c11 * (ww0 * p0.x + ww1 * p1.y);
            acc1 += c11 * (ww0 * p0.y + ww1 * p2.x);
            acc2 += c11 * (ww0 * p1.x + ww1 * p2.y);
        }
    } else {
        // boundary: per-corner bounds-checked gather (zeros padding)
        acc0 = acc1 = acc2 = 0.f;
        const __half* hp = (const __half*)in;
#pragma unroll
        for (int dz = 0; dz < 2; ++dz) {
            const int cd = d0 + dz;
            if ((unsigned)cd >= (unsigned)D_) continue;
            const float wz = dz ? fd : (1.f - fd);
#pragma unroll
            for (int dy = 0; dy < 2; ++dy) {
                const int ch = h0 + dy;
                if ((unsigned)ch >= (unsigned)H_) continue;
                const float wzy = wz * (dy ? fh : (1.f - fh));
                const int rowbase = (cd * H_ + ch) * W_;
#pragma unroll
                for (int dx = 0; dx < 2; ++dx) {
                    const int cw = w0 + dx;
                    if ((unsigned)cw >= (unsigned)W_) continue;
                    const float wt = wzy * (dx ? fw : (1.f - fw));
                    const int j = 3 * (rowbase + cw);
                    acc0 += wt * __half2float(hp[j]);
                    acc1 += wt * __half2float(hp[j + 1]);
                    acc2 += wt * __half2float(hp[j + 2]);
                }
            }
        }
    }

    const float o0 = f0 + acc0;
    const float o1 = f1 + acc1;
    const float o2 = f2 + acc2;
    if (PLANAR_OUT) {
        float* out = (float*)out_;
        out[idx]          = o0;
        out[NV + idx]     = o1;
        out[2 * NV + idx] = o2;
    } else {
        __half* out = (__half*)out_;
        out[3 * idx]     = __float2half_rn(o0);
        out[3 * idx + 1] = __float2half_rn(o1);
        out[3 * idx + 2] = __float2half_rn(o2);
    }
}

extern "C" void kernel_launch(void* const* d_in, const int* in_sizes, int n_in,
                              void* d_out, int out_size, void* d_ws, size_t ws_size,
                              hipStream_t stream) {
    const float* svf = (const float*)d_in[0];
    float* outp = (float*)d_out;           // final planar fp32 output
    u32* X0 = (u32*)d_ws;                  // fp16 scratch A (41.3 MB)
    u32* X1 = (u32*)d_out;                 // fp16 scratch B in d_out until last pass

    scale_k<<<NV / 4 / 256, 256, 0, stream>>>(svf, X0);

    dim3 blk(32, 4, 2);
    dim3 grd(NWG, 1, 1);

    compose_k<0><<<grd, blk, 0, stream>>>(X0, X1);
    compose_k<0><<<grd, blk, 0, stream>>>(X1, X0);
    compose_k<0><<<grd, blk, 0, stream>>>(X0, X1);
    compose_k<0><<<grd, blk, 0, stream>>>(X1, X0);
    compose_k<0><<<grd, blk, 0, stream>>>(X0, X1);
    compose_k<0><<<grd, blk, 0, stream>>>(X1, X0);
    compose_k<1><<<grd, blk, 0, stream>>>(X0, outp);
}